// Round 10
// baseline (303.057 us; speedup 1.0000x reference)
//
#include <hip/hip_runtime.h>
#include <cstdint>
#include <cstddef>

#define HD 128
#define KD 256
#define NBMAX 512
#define SLOT 2560

typedef __attribute__((ext_vector_type(8))) short bf16x8;
typedef __attribute__((ext_vector_type(4))) float f32x4;
typedef __attribute__((ext_vector_type(4))) unsigned int u32x4;
typedef __attribute__((ext_vector_type(2))) _Float16 h16x2;
typedef __attribute__((ext_vector_type(4))) _Float16 h16x4;

typedef const __attribute__((address_space(1))) void gv_t;
typedef __attribute__((address_space(3))) void lv_t;

__device__ __forceinline__ void gload16(const void* g, void* l) {
    __builtin_amdgcn_global_load_lds((gv_t*)g, (lv_t*)l, 16, 0, 0);
}

__device__ __forceinline__ unsigned short f2bf(float x) {   // RNE f32->bf16
    unsigned u = __float_as_uint(x);
    u = (u + 0x7fffu + ((u >> 16) & 1u)) >> 16;
    return (unsigned short)u;
}

// ===== pack B (blocks 0..15) + zero slot cursors (block 16). No race: =====
// ===== this dispatch completes before scatter starts (same stream).   =====
__global__ void pack_zero_kernel(const float* __restrict__ w1,
                                 unsigned short* __restrict__ Bp,
                                 int* __restrict__ cursor) {
    if (blockIdx.x == 16) {
        if (cursor) { cursor[threadIdx.x] = 0; cursor[threadIdx.x + 256] = 0; }
        return;
    }
    const int tid = blockIdx.x * 256 + threadIdx.x;   // 0..4095
    const int lane = tid & 63, nf = (tid >> 6) & 15, kt = tid >> 10;
    const int col = nf * 16 + (lane & 15);
    const int k0 = kt * 32 + (lane >> 4) * 8;
    #pragma unroll
    for (int j = 0; j < 8; ++j) {
        const int k = k0 + j;
        const float v = (col < HD) ? w1[(size_t)k * HD + col]
                                   : w1[(size_t)(HD + k) * HD + (col - HD)];
        Bp[(size_t)tid * 8 + j] = f2bf(v);
    }
}

// ===== slotted scatter: bucket b = src>>8, slot idx via atomic cursor =====
// entry: int2{ d, (s&255)<<20 | e }   (e < 2^20)
__global__ void scatter_slot_kernel(const int* __restrict__ eli, const int E,
                                    int* __restrict__ cursor,
                                    int2* __restrict__ sorted) {
    const int t0 = blockIdx.x * 256 + threadIdx.x;
    const int total = gridDim.x * 256;
    for (int e = t0; e < E; e += total) {
        const int s = eli[e], d = eli[E + e];
        const int b = s >> 8;
        const int idx = atomicAdd(&cursor[b], 1);
        if (idx < SLOT)
            sorted[(size_t)b * SLOT + idx] = make_int2(d, ((s & 255) << 20) | e);
    }
}

// ===== persistent uv_gemm: Bp staged ONCE, stride over 64-row tiles =====
// UV[n][c] f16: c<128 -> U' = z@W1a + b1 ; c>=128 -> V = z@W1b.
// Swapped-operand MFMA (D^T): lane owns one node, 4 consecutive cols/frag.
__global__ __launch_bounds__(256, 2) void uv_gemm_kernel(
    const float* __restrict__ z, const unsigned short* __restrict__ Bp,
    const float* __restrict__ b1, _Float16* __restrict__ UV, const int NN)
{
    __shared__ __attribute__((aligned(16))) unsigned short sA[64 * HD];   // 16 KB
    __shared__ __attribute__((aligned(16))) unsigned short sB[32 * 1024]; // 64 KB
    char* sAb = (char*)sA;
    const char* sBb = (const char*)sB;
    const int t = threadIdx.x, wave = t >> 6, l = t & 63;

    // stage Bp -> LDS once (64 x 1KB, 16 per wave)
    #pragma unroll
    for (int q = 0; q < 16; ++q) {
        const int i = wave * 16 + q;
        gload16((const char*)Bp + i * 1024 + l * 16, (char*)sB + i * 1024);
    }

    const int waveM = wave >> 1, waveN = wave & 1;
    const int ntiles = (NN + 63) >> 6;

    // bias fragment (constant across tiles)
    float4 bv[8];
    #pragma unroll
    for (int nf = 0; nf < 8; ++nf) {
        bv[nf] = make_float4(0.f, 0.f, 0.f, 0.f);
        if (waveN == 0) bv[nf] = *(const float4*)(b1 + nf * 16 + (l >> 4) * 4);
    }

    const int r = t >> 2, q4 = t & 3;   // staging role: 4 threads per row

    for (int tile = blockIdx.x; tile < ntiles; tile += gridDim.x) {
        const int n0 = tile * 64;
        // stage z tile f32 -> bf16 -> LDS (swizzled)
        {
            int n = n0 + r; if (n >= NN) n = NN - 1;
            const float* zr = z + (size_t)n * HD + q4 * 32;
            #pragma unroll
            for (int q = 0; q < 8; ++q) {
                const float4 v = *(const float4*)(zr + q * 4);
                ushort4 o;
                o.x = f2bf(v.x); o.y = f2bf(v.y); o.z = f2bf(v.z); o.w = f2bf(v.w);
                const int byte = r * 256 + (q4 * 32 + q * 4) * 2;
                *(ushort4*)(sAb + (byte ^ ((r & 15) << 4))) = o;
            }
        }
        __syncthreads();   // staging visible (also drains Bp gload16 on iter 0)

        f32x4 acc[2][8];
        #pragma unroll
        for (int nf = 0; nf < 8; ++nf)
            #pragma unroll
            for (int mf = 0; mf < 2; ++mf) {
                acc[mf][nf][0] = bv[nf].x; acc[mf][nf][1] = bv[nf].y;
                acc[mf][nf][2] = bv[nf].z; acc[mf][nf][3] = bv[nf].w;
            }
        #pragma unroll
        for (int kt = 0; kt < 4; ++kt) {
            bf16x8 bfr[8], af[2];
            #pragma unroll
            for (int nf = 0; nf < 8; ++nf)
                bfr[nf] = *(const bf16x8*)(sBb + (size_t)((kt * 16 + waveN * 8 + nf) * 64 + l) * 16);
            #pragma unroll
            for (int mf = 0; mf < 2; ++mf) {
                const int rr = waveM * 32 + mf * 16 + (l & 15);
                const int byte = rr * 256 + kt * 64 + (l >> 4) * 16;
                af[mf] = *(const bf16x8*)(sAb + (byte ^ ((rr & 15) << 4)));
            }
            #pragma unroll
            for (int mf = 0; mf < 2; ++mf)
                #pragma unroll
                for (int nf = 0; nf < 8; ++nf)
                    acc[mf][nf] = __builtin_amdgcn_mfma_f32_16x16x32_bf16(
                        bfr[nf], af[mf], acc[mf][nf], 0, 0, 0);   // swapped: D^T
        }
        #pragma unroll
        for (int mf = 0; mf < 2; ++mf) {
            const int n2 = n0 + waveM * 32 + mf * 16 + (l & 15);
            if (n2 < NN) {
                #pragma unroll
                for (int nf = 0; nf < 8; ++nf) {
                    const int c0 = waveN * 128 + nf * 16 + (l >> 4) * 4;
                    h16x4 o = (h16x4){(_Float16)acc[mf][nf][0], (_Float16)acc[mf][nf][1],
                                      (_Float16)acc[mf][nf][2], (_Float16)acc[mf][nf][3]};
                    *(h16x4*)(UV + (size_t)n2 * KD + c0) = o;
                }
            }
        }
        __syncthreads();   // all sA reads done before next tile's staging
    }
}

// ===== XCD-pinned slotted edge pass: 16 lanes/edge =====
__global__ __launch_bounds__(256, 8) void edge_slot_kernel(
    const _Float16* __restrict__ UV, const int2* __restrict__ sorted,
    const int* __restrict__ cursor, const int NB,
    const float* __restrict__ w2, const float* __restrict__ b2,
    float* __restrict__ out)
{
    const int t = threadIdx.x, cl = t & 15, g = t >> 4;
    const int xcd = blockIdx.x & 7, rank = blockIdx.x >> 3;   // ranks 0..255
    const int bpx = (NB + 7) >> 3;
    const int blo = xcd * bpx;
    if (blo >= NB) return;
    const int bhi = (blo + bpx < NB) ? (blo + bpx) : NB;
    const int nbk = bhi - blo;
    const int j = rank % nbk, sub = rank / nbk;
    const int nsub = (255 - j) / nbk + 1;
    const int b = blo + j;
    int cnt = cursor[b]; if (cnt > SLOT) cnt = SLOT;
    const size_t base = (size_t)b * SLOT;
    const int group = sub * 16 + g;
    const int stride = nsub * 16;

    h16x2 w2h[4];
    {
        const float4 wlo = *(const float4*)(w2 + cl * 8);
        const float4 whi = *(const float4*)(w2 + cl * 8 + 4);
        w2h[0] = (h16x2){(_Float16)wlo.x, (_Float16)wlo.y};
        w2h[1] = (h16x2){(_Float16)wlo.z, (_Float16)wlo.w};
        w2h[2] = (h16x2){(_Float16)whi.x, (_Float16)whi.y};
        w2h[3] = (h16x2){(_Float16)whi.z, (_Float16)whi.w};
    }
    const float bb2 = b2[0];
    const h16x2 zero2 = (h16x2){(_Float16)0.f, (_Float16)0.f};

    int i = group;
    if (i >= cnt) return;
    int2 q = sorted[base + i];
    int e = q.y & 0xFFFFF;
    int s = (b << 8) | ((q.y >> 20) & 255);
    u32x4 u = *(const u32x4*)(UV + (size_t)s * KD + cl * 8);
    u32x4 v = *(const u32x4*)(UV + (size_t)q.x * KD + HD + cl * 8);

    for (;;) {
        const int i2 = i + stride;
        int e2 = 0; u32x4 un, vn;
        if (i2 < cnt) {
            const int2 q2 = sorted[base + i2];
            e2 = q2.y & 0xFFFFF;
            const int s2 = (b << 8) | ((q2.y >> 20) & 255);
            un = *(const u32x4*)(UV + (size_t)s2 * KD + cl * 8);
            vn = *(const u32x4*)(UV + (size_t)q2.x * KD + HD + cl * 8);
        }
        h16x2 acc2 = zero2;
        #pragma unroll
        for (int m = 0; m < 4; ++m) {
            union { unsigned int ui; h16x2 h2; } cu, cv;
            cu.ui = u[m]; cv.ui = v[m];
            const h16x2 h = __builtin_elementwise_max(cu.h2 + cv.h2, zero2);
            acc2 = acc2 + h * w2h[m];
        }
        float acc = (float)acc2[0] + (float)acc2[1];
        #pragma unroll
        for (int msk = 1; msk <= 8; msk <<= 1) acc += __shfl_xor(acc, msk);
        if (cl == 0) out[e] = 1.f / (1.f + __expf(-(acc + bb2)));
        if (i2 >= cnt) break;
        i = i2; e = e2; u = un; v = vn;
    }
}

// ============== mid-tier fallback: unsorted edge pass ====================

__global__ __launch_bounds__(256, 8) void edge_uv_f16_kernel(
    const _Float16* __restrict__ UV, const int* __restrict__ eli,
    const int E, const float* __restrict__ w2, const float* __restrict__ b2,
    float* __restrict__ out)
{
    const int t = threadIdx.x;
    const int cl = t & 15;
    const int gid = (blockIdx.x * 256 + t) >> 4;
    const int ng = (gridDim.x * 256) >> 4;

    h16x2 w2h[4];
    {
        const float4 wlo = *(const float4*)(w2 + cl * 8);
        const float4 whi = *(const float4*)(w2 + cl * 8 + 4);
        w2h[0] = (h16x2){(_Float16)wlo.x, (_Float16)wlo.y};
        w2h[1] = (h16x2){(_Float16)wlo.z, (_Float16)wlo.w};
        w2h[2] = (h16x2){(_Float16)whi.x, (_Float16)whi.y};
        w2h[3] = (h16x2){(_Float16)whi.z, (_Float16)whi.w};
    }
    const float bb2 = b2[0];
    const h16x2 zero2 = (h16x2){(_Float16)0.f, (_Float16)0.f};

    int e = gid;
    if (e >= E) return;
    int s = eli[e], d = eli[E + e];
    u32x4 u = *(const u32x4*)(UV + (size_t)s * KD + cl * 8);
    u32x4 v = *(const u32x4*)(UV + (size_t)d * KD + HD + cl * 8);
    int en = e + ng;
    int enc = (en < E) ? en : (E - 1);
    int sn = eli[enc], dn = eli[E + enc];

    for (;;) {
        const int e2 = en + ng;
        const int e2c = (e2 < E) ? e2 : (E - 1);
        const int s2 = eli[e2c], d2 = eli[E + e2c];
        const u32x4 un = *(const u32x4*)(UV + (size_t)sn * KD + cl * 8);
        const u32x4 vn = *(const u32x4*)(UV + (size_t)dn * KD + HD + cl * 8);

        h16x2 acc2 = zero2;
        #pragma unroll
        for (int m = 0; m < 4; ++m) {
            union { unsigned int ui; h16x2 h2; } cu, cv;
            cu.ui = u[m]; cv.ui = v[m];
            const h16x2 h = __builtin_elementwise_max(cu.h2 + cv.h2, zero2);
            acc2 = acc2 + h * w2h[m];
        }
        float acc = (float)acc2[0] + (float)acc2[1];
        #pragma unroll
        for (int msk = 1; msk <= 8; msk <<= 1) acc += __shfl_xor(acc, msk);
        if (cl == 0) out[e] = 1.f / (1.f + __expf(-(acc + bb2)));

        if (en >= E) break;
        e = en; u = un; v = vn;
        en = e2; sn = s2; dn = d2;
    }
}

// ===================== last-resort fp32 fallback ==========================

__global__ __launch_bounds__(256, 2) void edge_decoder_fp32_kernel(
    const float* __restrict__ z, const int* __restrict__ eli, const int E,
    const float* __restrict__ w1, const float* __restrict__ b1,
    const float* __restrict__ w2, const float* __restrict__ b2,
    float* __restrict__ out)
{
    __shared__ float sZ[32][256];
    __shared__ float sW[2][32][128];
    const int t = threadIdx.x, wave = t >> 6, lane = t & 63;
    const int e0 = blockIdx.x * 32;
    #pragma unroll
    for (int q = 0; q < 8; ++q) {
        const int e = wave * 8 + q;
        int ge = e0 + e; if (ge >= E) ge = E - 1;
        const int node = (lane < 32) ? eli[ge] : eli[E + ge];
        gload16(z + (size_t)node * HD + (size_t)(lane & 31) * 4, &sZ[e][0]);
    }
    #pragma unroll
    for (int q = 0; q < 4; ++q) {
        const int inst = wave * 4 + q;
        gload16(w1 + inst * 256 + lane * 4, &sW[0][0][0] + inst * 256);
    }
    __syncthreads();
    const int cg = t & 31, eg = t >> 5, c0 = cg * 4;
    float acc[4][4] = {{0.f,0.f,0.f,0.f}};
    for (int kc = 0; kc < 8; ++kc) {
        const int buf = kc & 1;
        if (kc + 1 < 8) {
            const float* gw = w1 + (size_t)(kc + 1) * 32 * HD;
            #pragma unroll
            for (int q = 0; q < 4; ++q) {
                const int inst = wave * 4 + q;
                gload16(gw + inst * 256 + lane * 4, &sW[buf ^ 1][0][0] + inst * 256);
            }
        }
        #pragma unroll
        for (int k4 = 0; k4 < 8; ++k4) {
            float zr[4][4];
            #pragma unroll
            for (int i = 0; i < 4; ++i)
                *(float4*)(&zr[i][0]) = *(const float4*)(&sZ[eg*4+i][kc*32 + k4*4]);
            #pragma unroll
            for (int kk = 0; kk < 4; ++kk) {
                const float4 wv = *(const float4*)(&sW[buf][k4*4+kk][c0]);
                #pragma unroll
                for (int i = 0; i < 4; ++i) {
                    acc[i][0] = fmaf(zr[i][kk], wv.x, acc[i][0]);
                    acc[i][1] = fmaf(zr[i][kk], wv.y, acc[i][1]);
                    acc[i][2] = fmaf(zr[i][kk], wv.z, acc[i][2]);
                    acc[i][3] = fmaf(zr[i][kk], wv.w, acc[i][3]);
                }
            }
        }
        __syncthreads();
    }
    const float4 b1v = *(const float4*)(&b1[c0]);
    const float4 w2v = *(const float4*)(&w2[c0]);
    const float bb2 = b2[0];
    float part[4];
    #pragma unroll
    for (int i = 0; i < 4; ++i)
        part[i] = fmaxf(acc[i][0]+b1v.x,0.f)*w2v.x + fmaxf(acc[i][1]+b1v.y,0.f)*w2v.y
                + fmaxf(acc[i][2]+b1v.z,0.f)*w2v.z + fmaxf(acc[i][3]+b1v.w,0.f)*w2v.w;
    #pragma unroll
    for (int m = 16; m >= 1; m >>= 1)
        #pragma unroll
        for (int i = 0; i < 4; ++i) part[i] += __shfl_xor(part[i], m, 32);
    if (cg == 0) {
        #pragma unroll
        for (int i = 0; i < 4; ++i) {
            const int ge = e0 + eg * 4 + i;
            if (ge < E) out[ge] = 1.0f / (1.0f + __expf(-(part[i] + bb2)));
        }
    }
}

extern "C" void kernel_launch(void* const* d_in, const int* in_sizes, int n_in,
                              void* d_out, int out_size, void* d_ws, size_t ws_size,
                              hipStream_t stream) {
    const float* z  = (const float*)d_in[0];
    const int* eli  = (const int*)d_in[1];
    const float* w1 = (const float*)d_in[2];
    const float* b1 = (const float*)d_in[3];
    const float* w2 = (const float*)d_in[4];
    const float* b2 = (const float*)d_in[5];
    float* out = (float*)d_out;

    const int E  = in_sizes[1] / 2;
    const int NN = in_sizes[0] / HD;
    const int NB = (NN + 255) >> 8;

    size_t off = 0;
    auto take = [&](size_t n) { size_t r = off; off = (off + n + 15) & ~(size_t)15; return r; };
    const size_t o_uv    = take((size_t)NN * KD * 2);
    const size_t o_bp    = take(65536);
    const size_t need_uv = off;
    const size_t o_cur   = take(NBMAX * 4);
    const size_t o_sort  = take((size_t)NB * SLOT * 8);
    const size_t need_sorted = off;

    if (ws_size >= need_sorted && NB <= NBMAX && E < (1 << 20)) {
        _Float16* UV = (_Float16*)((char*)d_ws + o_uv);
        unsigned short* Bp = (unsigned short*)((char*)d_ws + o_bp);
        int* cursor  = (int*)((char*)d_ws + o_cur);
        int2* sorted = (int2*)((char*)d_ws + o_sort);

        pack_zero_kernel<<<17, 256, 0, stream>>>(w1, Bp, cursor);
        scatter_slot_kernel<<<512, 256, 0, stream>>>(eli, E, cursor, sorted);
        uv_gemm_kernel<<<512, 256, 0, stream>>>(z, Bp, b1, UV, NN);
        edge_slot_kernel<<<2048, 256, 0, stream>>>(UV, sorted, cursor, NB, w2, b2, out);
    } else if (ws_size >= need_uv) {
        _Float16* UV = (_Float16*)((char*)d_ws + o_uv);
        unsigned short* Bp = (unsigned short*)((char*)d_ws + o_bp);
        pack_zero_kernel<<<16, 256, 0, stream>>>(w1, Bp, (int*)nullptr);
        uv_gemm_kernel<<<512, 256, 0, stream>>>(z, Bp, b1, UV, NN);
        edge_uv_f16_kernel<<<2048, 256, 0, stream>>>(UV, eli, E, w2, b2, out);
    } else {
        edge_decoder_fp32_kernel<<<(E + 31) / 32, 256, 0, stream>>>(
            z, eli, E, w1, b1, w2, b2, out);
    }
}

// Round 11
// 93.811 us; speedup vs baseline: 3.2305x; 3.2305x over previous
//
#include <hip/hip_runtime.h>
#include <cstdint>
#include <cstddef>

#define HD 128
#define KD 256
#define NBMAX 512
#define SLOT 2560

typedef __attribute__((ext_vector_type(8))) short bf16x8;
typedef __attribute__((ext_vector_type(4))) float f32x4;
typedef __attribute__((ext_vector_type(4))) unsigned int u32x4;
typedef __attribute__((ext_vector_type(2))) _Float16 h16x2;
typedef __attribute__((ext_vector_type(4))) _Float16 h16x4;

typedef const __attribute__((address_space(1))) void gv_t;
typedef __attribute__((address_space(3))) void lv_t;

__device__ __forceinline__ void gload16(const void* g, void* l) {
    __builtin_amdgcn_global_load_lds((gv_t*)g, (lv_t*)l, 16, 0, 0);
}

__device__ __forceinline__ unsigned short f2bf(float x) {   // RNE f32->bf16
    unsigned u = __float_as_uint(x);
    u = (u + 0x7fffu + ((u >> 16) & 1u)) >> 16;
    return (unsigned short)u;
}

// ===== pack B (blocks 0..15) + zero slot cursors (block 16) =====
__global__ void pack_zero_kernel(const float* __restrict__ w1,
                                 unsigned short* __restrict__ Bp,
                                 int* __restrict__ cursor) {
    if (blockIdx.x == 16) {
        if (cursor) { cursor[threadIdx.x] = 0; cursor[threadIdx.x + 256] = 0; }
        return;
    }
    const int tid = blockIdx.x * 256 + threadIdx.x;   // 0..4095
    const int lane = tid & 63, nf = (tid >> 6) & 15, kt = tid >> 10;
    const int col = nf * 16 + (lane & 15);
    const int k0 = kt * 32 + (lane >> 4) * 8;
    #pragma unroll
    for (int j = 0; j < 8; ++j) {
        const int k = k0 + j;
        const float v = (col < HD) ? w1[(size_t)k * HD + col]
                                   : w1[(size_t)(HD + k) * HD + (col - HD)];
        Bp[(size_t)tid * 8 + j] = f2bf(v);
    }
}

// ===== LDS-aggregated slotted scatter (fix for round-10's 225us atomics) =====
// Per-block LDS histogram -> ONE cursor atomic per (block,bucket) reserving a
// contiguous range -> LDS-ranked scatter. Global atomics: 640K -> ~100K.
// entry: int2{ d, (s&255)<<20 | e }   (e < 2^20)
__global__ void scatter_slot_kernel(const int* __restrict__ eli, const int E,
                                    int* __restrict__ cursor,
                                    int2* __restrict__ sorted) {
    __shared__ int lh[NBMAX];
    __shared__ int lb[NBMAX];
    const int t = threadIdx.x;
    const int nb = NBMAX;   // zero full array (cheap) to avoid nb plumbing
    for (int b = t; b < nb; b += 256) lh[b] = 0;
    __syncthreads();
    const int per = (E + gridDim.x - 1) / gridDim.x;
    const int e0 = blockIdx.x * per;
    int e1 = e0 + per; if (e1 > E) e1 = E;
    for (int e = e0 + t; e < e1; e += 256)
        atomicAdd(&lh[eli[e] >> 8], 1);
    __syncthreads();
    for (int b = t; b < nb; b += 256) {
        const int c = lh[b];
        lb[b] = c ? atomicAdd(&cursor[b], c) : 0;
        lh[b] = 0;
    }
    __syncthreads();
    for (int e = e0 + t; e < e1; e += 256) {
        const int s = eli[e];
        const int b = s >> 8;
        const int r = atomicAdd(&lh[b], 1);
        const int idx = lb[b] + r;
        if (idx < SLOT)
            sorted[(size_t)b * SLOT + idx] = make_int2(eli[E + e], ((s & 255) << 20) | e);
    }
}

// ===== persistent uv_gemm: Bp staged ONCE, stride over 64-row tiles =====
// UV[n][c] f16: c<128 -> U' = z@W1a + b1 ; c>=128 -> V = z@W1b.
// Swapped-operand MFMA (D^T): lane owns one node, 4 consecutive cols/frag.
__global__ __launch_bounds__(256, 2) void uv_gemm_kernel(
    const float* __restrict__ z, const unsigned short* __restrict__ Bp,
    const float* __restrict__ b1, _Float16* __restrict__ UV, const int NN)
{
    __shared__ __attribute__((aligned(16))) unsigned short sA[64 * HD];   // 16 KB
    __shared__ __attribute__((aligned(16))) unsigned short sB[32 * 1024]; // 64 KB
    char* sAb = (char*)sA;
    const char* sBb = (const char*)sB;
    const int t = threadIdx.x, wave = t >> 6, l = t & 63;

    // stage Bp -> LDS once (64 x 1KB, 16 per wave)
    #pragma unroll
    for (int q = 0; q < 16; ++q) {
        const int i = wave * 16 + q;
        gload16((const char*)Bp + i * 1024 + l * 16, (char*)sB + i * 1024);
    }

    const int waveM = wave >> 1, waveN = wave & 1;
    const int ntiles = (NN + 63) >> 6;

    float4 bv[8];
    #pragma unroll
    for (int nf = 0; nf < 8; ++nf) {
        bv[nf] = make_float4(0.f, 0.f, 0.f, 0.f);
        if (waveN == 0) bv[nf] = *(const float4*)(b1 + nf * 16 + (l >> 4) * 4);
    }

    const int r = t >> 2, q4 = t & 3;   // staging role: 4 threads per row

    for (int tile = blockIdx.x; tile < ntiles; tile += gridDim.x) {
        const int n0 = tile * 64;
        {
            int n = n0 + r; if (n >= NN) n = NN - 1;
            const float* zr = z + (size_t)n * HD + q4 * 32;
            #pragma unroll
            for (int q = 0; q < 8; ++q) {
                const float4 v = *(const float4*)(zr + q * 4);
                ushort4 o;
                o.x = f2bf(v.x); o.y = f2bf(v.y); o.z = f2bf(v.z); o.w = f2bf(v.w);
                const int byte = r * 256 + (q4 * 32 + q * 4) * 2;
                *(ushort4*)(sAb + (byte ^ ((r & 15) << 4))) = o;
            }
        }
        __syncthreads();   // staging visible (also drains Bp gload16 on iter 0)

        f32x4 acc[2][8];
        #pragma unroll
        for (int nf = 0; nf < 8; ++nf)
            #pragma unroll
            for (int mf = 0; mf < 2; ++mf) {
                acc[mf][nf][0] = bv[nf].x; acc[mf][nf][1] = bv[nf].y;
                acc[mf][nf][2] = bv[nf].z; acc[mf][nf][3] = bv[nf].w;
            }
        #pragma unroll
        for (int kt = 0; kt < 4; ++kt) {
            bf16x8 bfr[8], af[2];
            #pragma unroll
            for (int nf = 0; nf < 8; ++nf)
                bfr[nf] = *(const bf16x8*)(sBb + (size_t)((kt * 16 + waveN * 8 + nf) * 64 + l) * 16);
            #pragma unroll
            for (int mf = 0; mf < 2; ++mf) {
                const int rr = waveM * 32 + mf * 16 + (l & 15);
                const int byte = rr * 256 + kt * 64 + (l >> 4) * 16;
                af[mf] = *(const bf16x8*)(sAb + (byte ^ ((rr & 15) << 4)));
            }
            #pragma unroll
            for (int mf = 0; mf < 2; ++mf)
                #pragma unroll
                for (int nf = 0; nf < 8; ++nf)
                    acc[mf][nf] = __builtin_amdgcn_mfma_f32_16x16x32_bf16(
                        bfr[nf], af[mf], acc[mf][nf], 0, 0, 0);   // swapped: D^T
        }
        #pragma unroll
        for (int mf = 0; mf < 2; ++mf) {
            const int n2 = n0 + waveM * 32 + mf * 16 + (l & 15);
            if (n2 < NN) {
                #pragma unroll
                for (int nf = 0; nf < 8; ++nf) {
                    const int c0 = waveN * 128 + nf * 16 + (l >> 4) * 4;
                    h16x4 o = (h16x4){(_Float16)acc[mf][nf][0], (_Float16)acc[mf][nf][1],
                                      (_Float16)acc[mf][nf][2], (_Float16)acc[mf][nf][3]};
                    *(h16x4*)(UV + (size_t)n2 * KD + c0) = o;
                }
            }
        }
        __syncthreads();   // all sA reads done before next tile's staging
    }
}

// ===== XCD-pinned slotted edge pass: 16 lanes/edge =====
__global__ __launch_bounds__(256, 8) void edge_slot_kernel(
    const _Float16* __restrict__ UV, const int2* __restrict__ sorted,
    const int* __restrict__ cursor, const int NB,
    const float* __restrict__ w2, const float* __restrict__ b2,
    float* __restrict__ out)
{
    const int t = threadIdx.x, cl = t & 15, g = t >> 4;
    const int xcd = blockIdx.x & 7, rank = blockIdx.x >> 3;   // ranks 0..255
    const int bpx = (NB + 7) >> 3;
    const int blo = xcd * bpx;
    if (blo >= NB) return;
    const int bhi = (blo + bpx < NB) ? (blo + bpx) : NB;
    const int nbk = bhi - blo;
    const int j = rank % nbk, sub = rank / nbk;
    const int nsub = (255 - j) / nbk + 1;
    const int b = blo + j;
    int cnt = cursor[b]; if (cnt > SLOT) cnt = SLOT;
    const size_t base = (size_t)b * SLOT;
    const int group = sub * 16 + g;
    const int stride = nsub * 16;

    h16x2 w2h[4];
    {
        const float4 wlo = *(const float4*)(w2 + cl * 8);
        const float4 whi = *(const float4*)(w2 + cl * 8 + 4);
        w2h[0] = (h16x2){(_Float16)wlo.x, (_Float16)wlo.y};
        w2h[1] = (h16x2){(_Float16)wlo.z, (_Float16)wlo.w};
        w2h[2] = (h16x2){(_Float16)whi.x, (_Float16)whi.y};
        w2h[3] = (h16x2){(_Float16)whi.z, (_Float16)whi.w};
    }
    const float bb2 = b2[0];
    const h16x2 zero2 = (h16x2){(_Float16)0.f, (_Float16)0.f};

    int i = group;
    if (i >= cnt) return;
    int2 q = sorted[base + i];
    int e = q.y & 0xFFFFF;
    int s = (b << 8) | ((q.y >> 20) & 255);
    u32x4 u = *(const u32x4*)(UV + (size_t)s * KD + cl * 8);
    u32x4 v = *(const u32x4*)(UV + (size_t)q.x * KD + HD + cl * 8);

    for (;;) {
        const int i2 = i + stride;
        int e2 = 0; u32x4 un, vn;
        if (i2 < cnt) {
            const int2 q2 = sorted[base + i2];
            e2 = q2.y & 0xFFFFF;
            const int s2 = (b << 8) | ((q2.y >> 20) & 255);
            un = *(const u32x4*)(UV + (size_t)s2 * KD + cl * 8);
            vn = *(const u32x4*)(UV + (size_t)q2.x * KD + HD + cl * 8);
        }
        h16x2 acc2 = zero2;
        #pragma unroll
        for (int m = 0; m < 4; ++m) {
            union { unsigned int ui; h16x2 h2; } cu, cv;
            cu.ui = u[m]; cv.ui = v[m];
            const h16x2 h = __builtin_elementwise_max(cu.h2 + cv.h2, zero2);
            acc2 = acc2 + h * w2h[m];
        }
        float acc = (float)acc2[0] + (float)acc2[1];
        #pragma unroll
        for (int msk = 1; msk <= 8; msk <<= 1) acc += __shfl_xor(acc, msk);
        if (cl == 0) out[e] = 1.f / (1.f + __expf(-(acc + bb2)));
        if (i2 >= cnt) break;
        i = i2; e = e2; u = un; v = vn;
    }
}

// ============== mid-tier fallback: unsorted edge pass ====================

__global__ __launch_bounds__(256, 8) void edge_uv_f16_kernel(
    const _Float16* __restrict__ UV, const int* __restrict__ eli,
    const int E, const float* __restrict__ w2, const float* __restrict__ b2,
    float* __restrict__ out)
{
    const int t = threadIdx.x;
    const int cl = t & 15;
    const int gid = (blockIdx.x * 256 + t) >> 4;
    const int ng = (gridDim.x * 256) >> 4;

    h16x2 w2h[4];
    {
        const float4 wlo = *(const float4*)(w2 + cl * 8);
        const float4 whi = *(const float4*)(w2 + cl * 8 + 4);
        w2h[0] = (h16x2){(_Float16)wlo.x, (_Float16)wlo.y};
        w2h[1] = (h16x2){(_Float16)wlo.z, (_Float16)wlo.w};
        w2h[2] = (h16x2){(_Float16)whi.x, (_Float16)whi.y};
        w2h[3] = (h16x2){(_Float16)whi.z, (_Float16)whi.w};
    }
    const float bb2 = b2[0];
    const h16x2 zero2 = (h16x2){(_Float16)0.f, (_Float16)0.f};

    int e = gid;
    if (e >= E) return;
    int s = eli[e], d = eli[E + e];
    u32x4 u = *(const u32x4*)(UV + (size_t)s * KD + cl * 8);
    u32x4 v = *(const u32x4*)(UV + (size_t)d * KD + HD + cl * 8);
    int en = e + ng;
    int enc = (en < E) ? en : (E - 1);
    int sn = eli[enc], dn = eli[E + enc];

    for (;;) {
        const int e2 = en + ng;
        const int e2c = (e2 < E) ? e2 : (E - 1);
        const int s2 = eli[e2c], d2 = eli[E + e2c];
        const u32x4 un = *(const u32x4*)(UV + (size_t)sn * KD + cl * 8);
        const u32x4 vn = *(const u32x4*)(UV + (size_t)dn * KD + HD + cl * 8);

        h16x2 acc2 = zero2;
        #pragma unroll
        for (int m = 0; m < 4; ++m) {
            union { unsigned int ui; h16x2 h2; } cu, cv;
            cu.ui = u[m]; cv.ui = v[m];
            const h16x2 h = __builtin_elementwise_max(cu.h2 + cv.h2, zero2);
            acc2 = acc2 + h * w2h[m];
        }
        float acc = (float)acc2[0] + (float)acc2[1];
        #pragma unroll
        for (int msk = 1; msk <= 8; msk <<= 1) acc += __shfl_xor(acc, msk);
        if (cl == 0) out[e] = 1.f / (1.f + __expf(-(acc + bb2)));

        if (en >= E) break;
        e = en; u = un; v = vn;
        en = e2; sn = s2; dn = d2;
    }
}

// ===================== last-resort fp32 fallback ==========================

__global__ __launch_bounds__(256, 2) void edge_decoder_fp32_kernel(
    const float* __restrict__ z, const int* __restrict__ eli, const int E,
    const float* __restrict__ w1, const float* __restrict__ b1,
    const float* __restrict__ w2, const float* __restrict__ b2,
    float* __restrict__ out)
{
    __shared__ float sZ[32][256];
    __shared__ float sW[2][32][128];
    const int t = threadIdx.x, wave = t >> 6, lane = t & 63;
    const int e0 = blockIdx.x * 32;
    #pragma unroll
    for (int q = 0; q < 8; ++q) {
        const int e = wave * 8 + q;
        int ge = e0 + e; if (ge >= E) ge = E - 1;
        const int node = (lane < 32) ? eli[ge] : eli[E + ge];
        gload16(z + (size_t)node * HD + (size_t)(lane & 31) * 4, &sZ[e][0]);
    }
    #pragma unroll
    for (int q = 0; q < 4; ++q) {
        const int inst = wave * 4 + q;
        gload16(w1 + inst * 256 + lane * 4, &sW[0][0][0] + inst * 256);
    }
    __syncthreads();
    const int cg = t & 31, eg = t >> 5, c0 = cg * 4;
    float acc[4][4] = {{0.f,0.f,0.f,0.f}};
    for (int kc = 0; kc < 8; ++kc) {
        const int buf = kc & 1;
        if (kc + 1 < 8) {
            const float* gw = w1 + (size_t)(kc + 1) * 32 * HD;
            #pragma unroll
            for (int q = 0; q < 4; ++q) {
                const int inst = wave * 4 + q;
                gload16(gw + inst * 256 + lane * 4, &sW[buf ^ 1][0][0] + inst * 256);
            }
        }
        #pragma unroll
        for (int k4 = 0; k4 < 8; ++k4) {
            float zr[4][4];
            #pragma unroll
            for (int i = 0; i < 4; ++i)
                *(float4*)(&zr[i][0]) = *(const float4*)(&sZ[eg*4+i][kc*32 + k4*4]);
            #pragma unroll
            for (int kk = 0; kk < 4; ++kk) {
                const float4 wv = *(const float4*)(&sW[buf][k4*4+kk][c0]);
                #pragma unroll
                for (int i = 0; i < 4; ++i) {
                    acc[i][0] = fmaf(zr[i][kk], wv.x, acc[i][0]);
                    acc[i][1] = fmaf(zr[i][kk], wv.y, acc[i][1]);
                    acc[i][2] = fmaf(zr[i][kk], wv.z, acc[i][2]);
                    acc[i][3] = fmaf(zr[i][kk], wv.w, acc[i][3]);
                }
            }
        }
        __syncthreads();
    }
    const float4 b1v = *(const float4*)(&b1[c0]);
    const float4 w2v = *(const float4*)(&w2[c0]);
    const float bb2 = b2[0];
    float part[4];
    #pragma unroll
    for (int i = 0; i < 4; ++i)
        part[i] = fmaxf(acc[i][0]+b1v.x,0.f)*w2v.x + fmaxf(acc[i][1]+b1v.y,0.f)*w2v.y
                + fmaxf(acc[i][2]+b1v.z,0.f)*w2v.z + fmaxf(acc[i][3]+b1v.w,0.f)*w2v.w;
    #pragma unroll
    for (int m = 16; m >= 1; m >>= 1)
        #pragma unroll
        for (int i = 0; i < 4; ++i) part[i] += __shfl_xor(part[i], m, 32);
    if (cg == 0) {
        #pragma unroll
        for (int i = 0; i < 4; ++i) {
            const int ge = e0 + eg * 4 + i;
            if (ge < E) out[ge] = 1.0f / (1.0f + __expf(-(part[i] + bb2)));
        }
    }
}

extern "C" void kernel_launch(void* const* d_in, const int* in_sizes, int n_in,
                              void* d_out, int out_size, void* d_ws, size_t ws_size,
                              hipStream_t stream) {
    const float* z  = (const float*)d_in[0];
    const int* eli  = (const int*)d_in[1];
    const float* w1 = (const float*)d_in[2];
    const float* b1 = (const float*)d_in[3];
    const float* w2 = (const float*)d_in[4];
    const float* b2 = (const float*)d_in[5];
    float* out = (float*)d_out;

    const int E  = in_sizes[1] / 2;
    const int NN = in_sizes[0] / HD;
    const int NB = (NN + 255) >> 8;

    size_t off = 0;
    auto take = [&](size_t n) { size_t r = off; off = (off + n + 15) & ~(size_t)15; return r; };
    const size_t o_uv    = take((size_t)NN * KD * 2);
    const size_t o_bp    = take(65536);
    const size_t need_uv = off;
    const size_t o_cur   = take(NBMAX * 4);
    const size_t o_sort  = take((size_t)NB * SLOT * 8);
    const size_t need_sorted = off;

    if (ws_size >= need_sorted && NB <= NBMAX && E < (1 << 20)) {
        _Float16* UV = (_Float16*)((char*)d_ws + o_uv);
        unsigned short* Bp = (unsigned short*)((char*)d_ws + o_bp);
        int* cursor  = (int*)((char*)d_ws + o_cur);
        int2* sorted = (int2*)((char*)d_ws + o_sort);

        pack_zero_kernel<<<17, 256, 0, stream>>>(w1, Bp, cursor);
        scatter_slot_kernel<<<256, 256, 0, stream>>>(eli, E, cursor, sorted);
        uv_gemm_kernel<<<512, 256, 0, stream>>>(z, Bp, b1, UV, NN);
        edge_slot_kernel<<<2048, 256, 0, stream>>>(UV, sorted, cursor, NB, w2, b2, out);
    } else if (ws_size >= need_uv) {
        _Float16* UV = (_Float16*)((char*)d_ws + o_uv);
        unsigned short* Bp = (unsigned short*)((char*)d_ws + o_bp);
        pack_zero_kernel<<<16, 256, 0, stream>>>(w1, Bp, (int*)nullptr);
        uv_gemm_kernel<<<512, 256, 0, stream>>>(z, Bp, b1, UV, NN);
        edge_uv_f16_kernel<<<2048, 256, 0, stream>>>(UV, eli, E, w2, b2, out);
    } else {
        edge_decoder_fp32_kernel<<<(E + 31) / 32, 256, 0, stream>>>(
            z, eli, E, w1, b1, w2, b2, out);
    }
}